// Round 4
// baseline (103.173 us; speedup 1.0000x reference)
//
#include <hip/hip_runtime.h>

#define DHALF  512     // D_CONTENT == D_POS
#define DEMB   1024
#define EPS    1e-3f

typedef float __attribute__((ext_vector_type(4))) f32x4;

__device__ __forceinline__ float4 f4add(float4 a, float4 b) {
    return make_float4(a.x + b.x, a.y + b.y, a.z + b.z, a.w + b.w);
}
__device__ __forceinline__ float f4sum(float4 a) { return a.x + a.y + a.z + a.w; }
__device__ __forceinline__ float f4sq(float4 a)  { return a.x*a.x + a.y*a.y + a.z*a.z + a.w*a.w; }

__device__ __forceinline__ void nt_store4(float4 v, float4* p) {
    f32x4 t; t.x = v.x; t.y = v.y; t.z = v.z; t.w = v.w;
    __builtin_nontemporal_store(t, (f32x4*)p);
}

__device__ __forceinline__ float4 norm4(float4 v, float mu, float inv,
                                        float4 av, float4 bv) {
    return make_float4((v.x - mu) * inv * av.x + bv.x,
                       (v.y - mu) * inv * av.y + bv.y,
                       (v.z - mu) * inv * av.z + bv.z,
                       (v.w - mu) * inv * av.w + bv.w);
}

__global__ __launch_bounds__(256, 4) void mle_kernel(
    const int* __restrict__ x0, const int* __restrict__ x1,
    const int* __restrict__ pos_ids,
    const float* __restrict__ emb0, const float* __restrict__ emb1,
    const float* __restrict__ post,
    const float* __restrict__ a2, const float* __restrict__ b2,
    float* __restrict__ ann, float* __restrict__ timing, int T)
{
    const int wid  = threadIdx.x >> 6;
    const int lane = threadIdx.x & 63;
    const int tokA = (blockIdx.x * 4 + wid) * 2;   // wave handles tokens tokA, tokA+1
    const int tokB = tokA + 1;
    if (tokA >= T) return;                          // T is a multiple of 8 in practice

    // --- indices for both tokens (issue everything up front for MLP) ---
    const int i0A = x0[tokA], i1A = x1[tokA], ipA = pos_ids[tokA];
    const int i0B = x0[tokB], i1B = x1[tokB], ipB = pos_ids[tokB];

    const float4* r0A = (const float4*)(emb0 + (size_t)i0A * DHALF);
    const float4* r1A = (const float4*)(emb1 + (size_t)i1A * DHALF);
    const float4* rpA = (const float4*)(post + (size_t)ipA * DHALF);
    const float4* r0B = (const float4*)(emb0 + (size_t)i0B * DHALF);
    const float4* r1B = (const float4*)(emb1 + (size_t)i1B * DHALF);
    const float4* rpB = (const float4*)(post + (size_t)ipB * DHALF);

    // --- gathers for both tokens (12 independent 1KB/wave loads in flight) ---
    float4 clA = f4add(r0A[lane],      r1A[lane]);
    float4 chA = f4add(r0A[lane + 64], r1A[lane + 64]);
    float4 tlA = rpA[lane];
    float4 thA = rpA[lane + 64];
    float4 clB = f4add(r0B[lane],      r1B[lane]);
    float4 chB = f4add(r0B[lane + 64], r1B[lane + 64]);
    float4 tlB = rpB[lane];
    float4 thB = rpB[lane + 64];

    // timing outputs are ready — stream them out before the reductions
    float4* timvA = (float4*)(timing + (size_t)tokA * DHALF);
    float4* timvB = (float4*)(timing + (size_t)tokB * DHALF);
    nt_store4(tlA, &timvA[lane]);
    nt_store4(thA, &timvA[lane + 64]);
    nt_store4(tlB, &timvB[lane]);
    nt_store4(thB, &timvB[lane + 64]);

    // a2/b2 (4KB each, cache-resident; shared by both tokens)
    const float4* Av = (const float4*)a2;
    const float4* Bv = (const float4*)b2;
    float4 acl = Av[lane],        bcl = Bv[lane];
    float4 ach = Av[lane + 64],   bch = Bv[lane + 64];
    float4 atl = Av[lane + 128],  btl = Bv[lane + 128];
    float4 ath = Av[lane + 192],  bth = Bv[lane + 192];

    // --- fused single-pass (sum, sumsq) reduction; A/B chains interleave ---
    float sA = f4sum(clA) + f4sum(chA) + f4sum(tlA) + f4sum(thA);
    float qA = f4sq(clA)  + f4sq(chA)  + f4sq(tlA)  + f4sq(thA);
    float sB = f4sum(clB) + f4sum(chB) + f4sum(tlB) + f4sum(thB);
    float qB = f4sq(clB)  + f4sq(chB)  + f4sq(tlB)  + f4sq(thB);
    #pragma unroll
    for (int off = 32; off > 0; off >>= 1) {
        sA += __shfl_xor(sA, off);
        qA += __shfl_xor(qA, off);
        sB += __shfl_xor(sB, off);
        qB += __shfl_xor(qB, off);
    }
    const float muA = sA * (1.0f / (float)DEMB);
    const float muB = sB * (1.0f / (float)DEMB);
    // unbiased variance: (sumsq - s*mu) / (N-1)
    const float varA = fmaxf(qA - sA * muA, 0.0f) * (1.0f / (float)(DEMB - 1));
    const float varB = fmaxf(qB - sB * muB, 0.0f) * (1.0f / (float)(DEMB - 1));
    const float invA = 1.0f / (sqrtf(varA) + EPS);
    const float invB = 1.0f / (sqrtf(varB) + EPS);

    // --- normalize + scale/shift + streaming stores ---
    float4* annvA = (float4*)(ann + (size_t)tokA * DEMB);
    float4* annvB = (float4*)(ann + (size_t)tokB * DEMB);

    nt_store4(norm4(clA, muA, invA, acl, bcl), &annvA[lane]);
    nt_store4(norm4(chA, muA, invA, ach, bch), &annvA[lane + 64]);
    nt_store4(norm4(tlA, muA, invA, atl, btl), &annvA[lane + 128]);
    nt_store4(norm4(thA, muA, invA, ath, bth), &annvA[lane + 192]);
    nt_store4(norm4(clB, muB, invB, acl, bcl), &annvB[lane]);
    nt_store4(norm4(chB, muB, invB, ach, bch), &annvB[lane + 64]);
    nt_store4(norm4(tlB, muB, invB, atl, btl), &annvB[lane + 128]);
    nt_store4(norm4(thB, muB, invB, ath, bth), &annvB[lane + 192]);
}

extern "C" void kernel_launch(void* const* d_in, const int* in_sizes, int n_in,
                              void* d_out, int out_size, void* d_ws, size_t ws_size,
                              hipStream_t stream) {
    const int*   x0     = (const int*)d_in[0];
    const int*   x1     = (const int*)d_in[1];
    const int*   pos    = (const int*)d_in[2];
    const float* emb0   = (const float*)d_in[3];
    const float* emb1   = (const float*)d_in[4];
    const float* ptab   = (const float*)d_in[5];
    const float* a2     = (const float*)d_in[6];
    const float* b2     = (const float*)d_in[7];

    const int T = in_sizes[0];                       // 65536 tokens
    float* out    = (float*)d_out;
    float* ann    = out;                             // [T, 1024]
    float* timing = out + (size_t)T * DEMB;          // [T, 512]

    const int threads = 256;                         // 4 waves; 2 tokens per wave
    const int blocks  = (T + 7) / 8;                 // 8 tokens per block
    mle_kernel<<<blocks, threads, 0, stream>>>(x0, x1, pos, emb0, emb1, ptab,
                                               a2, b2, ann, timing, T);
}

// Round 5
// 87.151 us; speedup vs baseline: 1.1838x; 1.1838x over previous
//
#include <hip/hip_runtime.h>

#define DHALF  512     // D_CONTENT == D_POS
#define DEMB   1024
#define EPS    1e-3f
#define NSEQ   32

typedef float __attribute__((ext_vector_type(4))) f32x4;

// Ragged position-major rank decode table (host-built, static problem geometry).
// Segment k covers positions [P[k], P[k+1]) where sequences k..31 are active
// (lens ascending). R[k] = first rank of segment k; R[32] = T.
struct SegTable {
    int R[33];
    int P[33];
    int off[NSEQ];
};

__device__ __forceinline__ float4 f4add(float4 a, float4 b) {
    return make_float4(a.x + b.x, a.y + b.y, a.z + b.z, a.w + b.w);
}
__device__ __forceinline__ float f4sum(float4 a) { return a.x + a.y + a.z + a.w; }
__device__ __forceinline__ float f4sq(float4 a)  { return a.x*a.x + a.y*a.y + a.z*a.z + a.w*a.w; }

__device__ __forceinline__ void nt_store4(float4 v, float4* p) {
    f32x4 t; t.x = v.x; t.y = v.y; t.z = v.z; t.w = v.w;
    __builtin_nontemporal_store(t, (f32x4*)p);
}

__device__ __forceinline__ float4 norm4(float4 v, float mu, float inv,
                                        float4 av, float4 bv) {
    return make_float4((v.x - mu) * inv * av.x + bv.x,
                       (v.y - mu) * inv * av.y + bv.y,
                       (v.z - mu) * inv * av.z + bv.z,
                       (v.w - mu) * inv * av.w + bv.w);
}

// rank (position-major) -> token index
__device__ __forceinline__ int decode_tok(int r, const SegTable& st) {
    int k = 0;
    while (r >= st.R[k + 1]) ++k;          // <= 32 iterations, wave-uniform
    const int d = r - st.R[k];
    const int w = NSEQ - k;                // active sequence count
    const int p = st.P[k] + d / w;
    const int j = d % w;
    return st.off[k + j] + p;
}

__global__ __launch_bounds__(256, 4) void mle_kernel(
    const int* __restrict__ x0, const int* __restrict__ x1,
    const int* __restrict__ pos_ids,
    const float* __restrict__ emb0, const float* __restrict__ emb1,
    const float* __restrict__ post,
    const float* __restrict__ a2, const float* __restrict__ b2,
    float* __restrict__ ann, float* __restrict__ timing,
    SegTable st, int T)
{
    const int wid  = threadIdx.x >> 6;
    const int lane = threadIdx.x & 63;

    // bijective XCD-chunked swizzle: each XCD gets a contiguous rank range
    const int nwg  = gridDim.x;
    const int q    = nwg >> 3;
    const int rr   = nwg & 7;
    const int xcd  = blockIdx.x & 7;
    const int idx  = blockIdx.x >> 3;
    const int swz  = (xcd < rr ? xcd * (q + 1) : rr * (q + 1) + (xcd - rr) * q) + idx;

    const int gw = swz * 4 + wid;          // global wave id
    const int rA = gw * 2;                 // two position-major ranks per wave
    const int rB = rA + 1;
    if (rA >= T) return;

    const int tokA = decode_tok(rA, st);
    const int tokB = decode_tok(rB, st);

    // --- indices for both tokens ---
    const int i0A = x0[tokA], i1A = x1[tokA], ipA = pos_ids[tokA];
    const int i0B = x0[tokB], i1B = x1[tokB], ipB = pos_ids[tokB];

    const float4* r0A = (const float4*)(emb0 + (size_t)i0A * DHALF);
    const float4* r1A = (const float4*)(emb1 + (size_t)i1A * DHALF);
    const float4* rpA = (const float4*)(post + (size_t)ipA * DHALF);
    const float4* r0B = (const float4*)(emb0 + (size_t)i0B * DHALF);
    const float4* r1B = (const float4*)(emb1 + (size_t)i1B * DHALF);
    const float4* rpB = (const float4*)(post + (size_t)ipB * DHALF);

    // --- gathers (same-p neighbors now hit L1/L2 for the pos rows) ---
    float4 clA = f4add(r0A[lane],      r1A[lane]);
    float4 chA = f4add(r0A[lane + 64], r1A[lane + 64]);
    float4 tlA = rpA[lane];
    float4 thA = rpA[lane + 64];
    float4 clB = f4add(r0B[lane],      r1B[lane]);
    float4 chB = f4add(r0B[lane + 64], r1B[lane + 64]);
    float4 tlB = rpB[lane];
    float4 thB = rpB[lane + 64];

    // timing outputs ready — stream out before the reductions
    float4* timvA = (float4*)(timing + (size_t)tokA * DHALF);
    float4* timvB = (float4*)(timing + (size_t)tokB * DHALF);
    nt_store4(tlA, &timvA[lane]);
    nt_store4(thA, &timvA[lane + 64]);
    nt_store4(tlB, &timvB[lane]);
    nt_store4(thB, &timvB[lane + 64]);

    // a2/b2 (4KB each, cache-resident; shared by both tokens)
    const float4* Av = (const float4*)a2;
    const float4* Bv = (const float4*)b2;
    float4 acl = Av[lane],        bcl = Bv[lane];
    float4 ach = Av[lane + 64],   bch = Bv[lane + 64];
    float4 atl = Av[lane + 128],  btl = Bv[lane + 128];
    float4 ath = Av[lane + 192],  bth = Bv[lane + 192];

    // --- fused single-pass (sum, sumsq) reduction; A/B chains interleave ---
    float sA = f4sum(clA) + f4sum(chA) + f4sum(tlA) + f4sum(thA);
    float qA = f4sq(clA)  + f4sq(chA)  + f4sq(tlA)  + f4sq(thA);
    float sB = f4sum(clB) + f4sum(chB) + f4sum(tlB) + f4sum(thB);
    float qB = f4sq(clB)  + f4sq(chB)  + f4sq(tlB)  + f4sq(thB);
    #pragma unroll
    for (int off = 32; off > 0; off >>= 1) {
        sA += __shfl_xor(sA, off);
        qA += __shfl_xor(qA, off);
        sB += __shfl_xor(sB, off);
        qB += __shfl_xor(qB, off);
    }
    const float muA = sA * (1.0f / (float)DEMB);
    const float muB = sB * (1.0f / (float)DEMB);
    const float varA = fmaxf(qA - sA * muA, 0.0f) * (1.0f / (float)(DEMB - 1));
    const float varB = fmaxf(qB - sB * muB, 0.0f) * (1.0f / (float)(DEMB - 1));
    const float invA = 1.0f / (sqrtf(varA) + EPS);
    const float invB = 1.0f / (sqrtf(varB) + EPS);

    // --- normalize + scale/shift + streaming stores ---
    float4* annvA = (float4*)(ann + (size_t)tokA * DEMB);
    float4* annvB = (float4*)(ann + (size_t)tokB * DEMB);

    nt_store4(norm4(clA, muA, invA, acl, bcl), &annvA[lane]);
    nt_store4(norm4(chA, muA, invA, ach, bch), &annvA[lane + 64]);
    nt_store4(norm4(tlA, muA, invA, atl, btl), &annvA[lane + 128]);
    nt_store4(norm4(thA, muA, invA, ath, bth), &annvA[lane + 192]);
    nt_store4(norm4(clB, muB, invB, acl, bcl), &annvB[lane]);
    nt_store4(norm4(chB, muB, invB, ach, bch), &annvB[lane + 64]);
    nt_store4(norm4(tlB, muB, invB, atl, btl), &annvB[lane + 128]);
    nt_store4(norm4(thB, muB, invB, ath, bth), &annvB[lane + 192]);
}

extern "C" void kernel_launch(void* const* d_in, const int* in_sizes, int n_in,
                              void* d_out, int out_size, void* d_ws, size_t ws_size,
                              hipStream_t stream) {
    const int*   x0     = (const int*)d_in[0];
    const int*   x1     = (const int*)d_in[1];
    const int*   pos    = (const int*)d_in[2];
    const float* emb0   = (const float*)d_in[3];
    const float* emb1   = (const float*)d_in[4];
    const float* ptab   = (const float*)d_in[5];
    const float* a2     = (const float*)d_in[6];
    const float* b2     = (const float*)d_in[7];

    const int T = in_sizes[0];                       // 65536 tokens
    float* out    = (float*)d_out;
    float* ann    = out;                             // [T, 1024]
    float* timing = out + (size_t)T * DEMB;          // [T, 512]

    // --- host-side ragged geometry (static per the reference) ---
    long long lens[NSEQ]; long long sum = 0;
    for (int i = 0; i < NSEQ; ++i) { lens[i] = 1024 + 66LL * i; sum += lens[i]; }
    lens[NSEQ - 1] += (long long)T - sum;            // lens now sum to T, ascending

    SegTable st;
    { int acc = 0;
      for (int i = 0; i < NSEQ; ++i) { st.off[i] = acc; acc += (int)lens[i]; } }
    st.P[0] = 0;
    for (int k = 1; k <= NSEQ; ++k) st.P[k] = (int)lens[k - 1];
    st.R[0] = 0;
    for (int k = 0; k < NSEQ; ++k)
        st.R[k + 1] = st.R[k] + (st.P[k + 1] - st.P[k]) * (NSEQ - k);
    // st.R[NSEQ] == T by construction

    const int threads = 256;                         // 4 waves; 2 tokens per wave
    const int blocks  = (T + 7) / 8;                 // 8 tokens per block
    mle_kernel<<<blocks, threads, 0, stream>>>(x0, x1, pos, emb0, emb1, ptab,
                                               a2, b2, ann, timing, st, T);
}